// Round 1
// baseline (746.621 us; speedup 1.0000x reference)
//
#include <hip/hip_runtime.h>

// TPF encoder, MFMA fp16 version.
// Per level: edge MLP (256->128, 128->128, both LN+relu) -> atomic segment-sum ->
// node MLP (256->128, 128->128, head 256->128, all LN+relu).
//
// - Weights packed per launch to Wp[kb][n][kk] fp16 (kk = 32 k-values contiguous):
//   B-fragment of mfma_f32_16x16x32 is one 16B load/lane, wave reads 1KB contiguous.
// - Activations staged in LDS fp16, row stride 264 (264*2B=528B = 132 dwords, 132%32=4
//   -> bank-balanced ds_read_b128 A-frags and staging writes).
// - s_y ALIASED into s_x upper half (s_x + 128, stride XS): the [h|bond] / [ax|agg]
//   second half of each row is dead after GEMM1 (ln_relu's __syncthreads guarantees
//   all waves finished reading before f1 is written). Cuts LDS 26624 -> 17920 B,
//   unlocking 8 blocks/CU (32 waves, 100% occupancy) vs 6 before. Kernel is
//   latency-bound (MfmaUtil 5%, VALUBusy 18%, HBM 16%), so occupancy is the lever.
// - LayerNorm in-register from MFMA C/D layout: per-lane partials over 4 col-tiles,
//   shuffle-xor over the 16-lane n-group, tiny LDS combine across the 2 col-half waves.
// - Block = 32 rows, 256 threads = 4 waves; wave w: rows 16*(w&1), cols 64*(w>>1),
//   per wave 4 16x16 tiles (acc = 4x f32x4).
// - h1 intermediate kept in fp16 (halves iter-1 gather traffic). agg fp32 + atomicAdd.

#define D   128
#define TE  32
#define XS  264   // s_x row stride in fp16 elems (s_y lives at +128, same stride)

typedef float  f32x4 __attribute__((ext_vector_type(4)));
typedef _Float16 f16x8 __attribute__((ext_vector_type(8)));

__device__ __forceinline__ unsigned short f2h(float f) {
    union { _Float16 h; unsigned short u; } x;
    x.h = (_Float16)f;
    return x.u;
}

// ---- weight pack: Wp[kb*4096 + n*32 + kk] = fp16(W[kb*32+kk][n]) per matrix,level ----
__global__ __launch_bounds__(256) void pack_w(
    const float* __restrict__ brW1, const float* __restrict__ brW2,
    const float* __restrict__ sW1,  const float* __restrict__ sW2,
    const float* __restrict__ hW,   unsigned short* __restrict__ Wp)
{
    int p = blockIdx.x * 256 + threadIdx.x;   // 0 .. 262143
    const float* src; int off, K;
    if (p < 65536)       { src = brW1; off = 0;      K = 256; }
    else if (p < 98304)  { src = brW2; off = 65536;  K = 128; }
    else if (p < 163840) { src = sW1;  off = 98304;  K = 256; }
    else if (p < 196608) { src = sW2;  off = 163840; K = 128; }
    else                 { src = hW;   off = 196608; K = 256; }
    int q = p - off, lvl, r;
    if (K == 256) { lvl = q >> 15; r = q & 32767; }
    else          { lvl = q >> 14; r = q & 16383; }
    int kb = r >> 12, n = (r >> 5) & 127, kk = r & 31;
    Wp[p] = f2h(src[(size_t)lvl * K * 128 + (size_t)(kb * 32 + kk) * 128 + n]);
}

template<int KB>
__device__ __forceinline__ void gemm_f16(const unsigned short* s_in, int stride,
    const unsigned short* __restrict__ Wp, int rb, int cb, int n15, int q, f32x4 acc[4])
{
    f32x4 zero = {0.f, 0.f, 0.f, 0.f};
#pragma unroll
    for (int ct = 0; ct < 4; ++ct) acc[ct] = zero;
#pragma unroll
    for (int kb = 0; kb < KB; ++kb) {
        f16x8 af = *(const f16x8*)(s_in + (rb + n15) * stride + kb * 32 + q * 8);
        const unsigned short* wb = Wp + (size_t)kb * 4096 + q * 8;
#pragma unroll
        for (int ct = 0; ct < 4; ++ct) {
            f16x8 bf = *(const f16x8*)(wb + (cb + ct * 16 + n15) * 32);
            acc[ct] = __builtin_amdgcn_mfma_f32_16x16x32_f16(af, bf, acc[ct], 0, 0, 0);
        }
    }
}

// bias + LayerNorm + relu, in-place on acc (MFMA C layout: row=rb+q*4+r, col=cb+ct*16+n15)
__device__ __forceinline__ void ln_relu(f32x4 acc[4],
    const float* __restrict__ b, const float* __restrict__ g, const float* __restrict__ be,
    float* s_red, float* s_ms, int rb, int cb, int n15, int q, int wcol, int t)
{
#pragma unroll
    for (int ct = 0; ct < 4; ++ct) {
        float bb = b[cb + ct * 16 + n15];
#pragma unroll
        for (int r = 0; r < 4; ++r) acc[ct][r] += bb;
    }
    float sum[4], ss[4];
#pragma unroll
    for (int r = 0; r < 4; ++r) {
        sum[r] = acc[0][r] + acc[1][r] + acc[2][r] + acc[3][r];
        ss[r]  = acc[0][r]*acc[0][r] + acc[1][r]*acc[1][r]
               + acc[2][r]*acc[2][r] + acc[3][r]*acc[3][r];
    }
#pragma unroll
    for (int off = 1; off < 16; off <<= 1) {
#pragma unroll
        for (int r = 0; r < 4; ++r) {
            sum[r] += __shfl_xor(sum[r], off, 64);
            ss[r]  += __shfl_xor(ss[r],  off, 64);
        }
    }
    if (n15 == 0) {
#pragma unroll
        for (int r = 0; r < 4; ++r) {
            int row = rb + q * 4 + r;
            s_red[row * 4 + wcol * 2 + 0] = sum[r];
            s_red[row * 4 + wcol * 2 + 1] = ss[r];
        }
    }
    __syncthreads();
    if (t < TE) {
        float sm = s_red[t * 4 + 0] + s_red[t * 4 + 2];
        float sq = s_red[t * 4 + 1] + s_red[t * 4 + 3];
        float mean = sm * (1.f / 128.f);
        float var  = sq * (1.f / 128.f) - mean * mean;
        s_ms[t * 2 + 0] = mean;
        s_ms[t * 2 + 1] = rsqrtf(var + 1e-5f);
    }
    __syncthreads();
#pragma unroll
    for (int ct = 0; ct < 4; ++ct) {
        float gg = g[cb + ct * 16 + n15], bb = be[cb + ct * 16 + n15];
#pragma unroll
        for (int r = 0; r < 4; ++r) {
            int row = rb + q * 4 + r;
            float v = (acc[ct][r] - s_ms[row * 2 + 0]) * s_ms[row * 2 + 1] * gg + bb;
            acc[ct][r] = fmaxf(v, 0.f);
        }
    }
}

template<bool HBF16>
__global__ __launch_bounds__(256, 8) void edge_mlp(
    const void* __restrict__ hsrc, const float* __restrict__ bond,
    const int* __restrict__ src, const int* __restrict__ dst,
    const unsigned short* __restrict__ Wp1, const unsigned short* __restrict__ Wp2,
    const float* __restrict__ b1, const float* __restrict__ g1, const float* __restrict__ be1,
    const float* __restrict__ b2, const float* __restrict__ g2, const float* __restrict__ be2,
    float* __restrict__ agg, int E)
{
    __shared__ unsigned short s_x[TE * XS];
    __shared__ float s_red[TE * 4];
    __shared__ float s_ms[TE * 2];
    __shared__ int s_src[TE], s_dst[TE];
    unsigned short* s_y = s_x + 128;   // aliased f1 buffer (cols 128..255 dead after GEMM1)

    int t = threadIdx.x, eb = blockIdx.x * TE;
    if (t < TE) {
        int ge = eb + t;
        s_src[t] = (ge < E) ? src[ge] : -1;
        s_dst[t] = (ge < E) ? dst[ge] : -1;
    }
    __syncthreads();

    if (HBF16) {   // h is fp16 (our h1 intermediate)
        const unsigned short* hp = (const unsigned short*)hsrc;
        for (int c = t; c < TE * 16; c += 256) {
            int row = c >> 4, k8 = c & 15;
            int s = s_src[row];
            uint4 v = make_uint4(0, 0, 0, 0);
            if (s >= 0) v = *(const uint4*)(hp + (size_t)s * 128 + k8 * 8);
            *(uint4*)(s_x + row * XS + k8 * 8) = v;
        }
    } else {       // h is fp32 (input subtree_h_top)
        const float* hp = (const float*)hsrc;
        for (int c = t; c < TE * 32; c += 256) {
            int row = c >> 5, k4 = c & 31;
            int s = s_src[row];
            float4 v = make_float4(0, 0, 0, 0);
            if (s >= 0) v = *(const float4*)(hp + (size_t)s * 128 + k4 * 4);
            ushort4 o; o.x = f2h(v.x); o.y = f2h(v.y); o.z = f2h(v.z); o.w = f2h(v.w);
            *(ushort4*)(s_x + row * XS + k4 * 4) = o;
        }
    }
    for (int c = t; c < TE * 32; c += 256) {   // bond part (always fp32)
        int row = c >> 5, k4 = c & 31;
        int ge = eb + row;
        float4 v = make_float4(0, 0, 0, 0);
        if (ge < E) v = *(const float4*)(bond + (size_t)ge * 128 + k4 * 4);
        ushort4 o; o.x = f2h(v.x); o.y = f2h(v.y); o.z = f2h(v.z); o.w = f2h(v.w);
        *(ushort4*)(s_x + row * XS + 128 + k4 * 4) = o;
    }
    __syncthreads();

    int l = t & 63, w = t >> 6;
    int n15 = l & 15, q = l >> 4;
    int rb = (w & 1) * 16, cb = (w >> 1) * 64, wcol = w >> 1;

    f32x4 acc[4];
    gemm_f16<8>(s_x, XS, Wp1, rb, cb, n15, q, acc);
    ln_relu(acc, b1, g1, be1, s_red, s_ms, rb, cb, n15, q, wcol, t);
    // ln_relu's internal barriers guarantee all waves finished reading s_x before this write
#pragma unroll
    for (int ct = 0; ct < 4; ++ct)
#pragma unroll
        for (int r = 0; r < 4; ++r)
            s_y[(rb + q * 4 + r) * XS + cb + ct * 16 + n15] = f2h(acc[ct][r]);
    __syncthreads();
    gemm_f16<4>(s_y, XS, Wp2, rb, cb, n15, q, acc);
    ln_relu(acc, b2, g2, be2, s_red, s_ms, rb, cb, n15, q, wcol, t);

#pragma unroll
    for (int ct = 0; ct < 4; ++ct)
#pragma unroll
        for (int r = 0; r < 4; ++r) {
            int row = rb + q * 4 + r;
            int gd = s_dst[row];
            if (gd >= 0)
                atomicAdd(agg + (size_t)gd * D + cb + ct * 16 + n15, acc[ct][r]);
        }
}

template<bool OUT_F16>
__global__ __launch_bounds__(256, 8) void node_mlp(
    const float* __restrict__ ax, const float* __restrict__ agg,
    const unsigned short* __restrict__ Wp1, const unsigned short* __restrict__ Wp2,
    const unsigned short* __restrict__ Wp3,
    const float* __restrict__ b1, const float* __restrict__ g1, const float* __restrict__ be1,
    const float* __restrict__ b2, const float* __restrict__ g2, const float* __restrict__ be2,
    const float* __restrict__ b3, const float* __restrict__ g3, const float* __restrict__ be3,
    void* __restrict__ out, int N)
{
    __shared__ unsigned short s_x[TE * XS];
    __shared__ float s_red[TE * 4];
    __shared__ float s_ms[TE * 2];
    unsigned short* s_y = s_x + 128;   // aliased f1 buffer

    int t = threadIdx.x, nb = blockIdx.x * TE;

    for (int c = t; c < TE * 32; c += 256) {   // ax part
        int row = c >> 5, k4 = c & 31;
        int gr = nb + row;
        float4 v = make_float4(0, 0, 0, 0);
        if (gr < N) v = *(const float4*)(ax + (size_t)gr * 128 + k4 * 4);
        ushort4 o; o.x = f2h(v.x); o.y = f2h(v.y); o.z = f2h(v.z); o.w = f2h(v.w);
        *(ushort4*)(s_x + row * XS + k4 * 4) = o;
    }
    for (int c = t; c < TE * 32; c += 256) {   // agg part
        int row = c >> 5, k4 = c & 31;
        int gr = nb + row;
        float4 v = make_float4(0, 0, 0, 0);
        if (gr < N) v = *(const float4*)(agg + (size_t)gr * 128 + k4 * 4);
        ushort4 o; o.x = f2h(v.x); o.y = f2h(v.y); o.z = f2h(v.z); o.w = f2h(v.w);
        *(ushort4*)(s_x + row * XS + 128 + k4 * 4) = o;
    }
    __syncthreads();

    int l = t & 63, w = t >> 6;
    int n15 = l & 15, q = l >> 4;
    int rb = (w & 1) * 16, cb = (w >> 1) * 64, wcol = w >> 1;

    f32x4 acc[4];
    gemm_f16<8>(s_x, XS, Wp1, rb, cb, n15, q, acc);
    ln_relu(acc, b1, g1, be1, s_red, s_ms, rb, cb, n15, q, wcol, t);
    // agg half of s_x consumed (barriers in ln_relu) -> safe to overwrite with f1
#pragma unroll
    for (int ct = 0; ct < 4; ++ct)
#pragma unroll
        for (int r = 0; r < 4; ++r)
            s_y[(rb + q * 4 + r) * XS + cb + ct * 16 + n15] = f2h(acc[ct][r]);
    __syncthreads();
    gemm_f16<4>(s_y, XS, Wp2, rb, cb, n15, q, acc);
    ln_relu(acc, b2, g2, be2, s_red, s_ms, rb, cb, n15, q, wcol, t);
#pragma unroll
    for (int ct = 0; ct < 4; ++ct)    // f2 -> s_x cols 128..255 (th = [ax | f2]); f1 dead
#pragma unroll
        for (int r = 0; r < 4; ++r)
            s_x[(rb + q * 4 + r) * XS + 128 + cb + ct * 16 + n15] = f2h(acc[ct][r]);
    __syncthreads();
    gemm_f16<8>(s_x, XS, Wp3, rb, cb, n15, q, acc);
    ln_relu(acc, b3, g3, be3, s_red, s_ms, rb, cb, n15, q, wcol, t);

#pragma unroll
    for (int ct = 0; ct < 4; ++ct)
#pragma unroll
        for (int r = 0; r < 4; ++r) {
            int row = rb + q * 4 + r;
            int gr = nb + row;
            int col = cb + ct * 16 + n15;
            if (gr < N) {
                if (OUT_F16)
                    ((unsigned short*)out)[(size_t)gr * D + col] = f2h(acc[ct][r]);
                else
                    ((float*)out)[(size_t)gr * D + col] = acc[ct][r];
            }
        }
}

extern "C" void kernel_launch(void* const* d_in, const int* in_sizes, int n_in,
                              void* d_out, int out_size, void* d_ws, size_t ws_size,
                              hipStream_t stream)
{
    const float* h2   = (const float*)d_in[0];
    const float* ax1  = (const float*)d_in[1];
    const float* ax0  = (const float*)d_in[2];
    const float* bx2  = (const float*)d_in[3];
    const float* bx1  = (const float*)d_in[4];
    const float* brW1 = (const float*)d_in[5];
    const float* brb1 = (const float*)d_in[6];
    const float* brg1 = (const float*)d_in[7];
    const float* brbe1= (const float*)d_in[8];
    const float* brW2 = (const float*)d_in[9];
    const float* brb2 = (const float*)d_in[10];
    const float* brg2 = (const float*)d_in[11];
    const float* brbe2= (const float*)d_in[12];
    const float* sW1  = (const float*)d_in[13];
    const float* sb1  = (const float*)d_in[14];
    const float* sg1  = (const float*)d_in[15];
    const float* sbe1 = (const float*)d_in[16];
    const float* sW2  = (const float*)d_in[17];
    const float* sb2  = (const float*)d_in[18];
    const float* sg2  = (const float*)d_in[19];
    const float* sbe2 = (const float*)d_in[20];
    const float* hW   = (const float*)d_in[21];
    const float* hb   = (const float*)d_in[22];
    const float* hg   = (const float*)d_in[23];
    const float* hbe  = (const float*)d_in[24];
    const int*   src2 = (const int*)d_in[25];
    const int*   dst2 = (const int*)d_in[26];
    const int*   src1 = (const int*)d_in[27];
    const int*   dst1 = (const int*)d_in[28];

    int n2 = in_sizes[0] / D;
    int n1 = in_sizes[1] / D;
    int n0 = in_sizes[2] / D;

    // workspace layout
    unsigned short* Wp  = (unsigned short*)d_ws;          // 262144 fp16 = 512 KB
    float*          agg = (float*)((char*)d_ws + 524288); // n1*128 fp32 (reused for n0)
    unsigned short* h1  = (unsigned short*)(agg + (size_t)n1 * D); // n1*128 fp16

    // packed-weight pointers (level stride)
    const unsigned short* pBr1[2] = { Wp + 0,      Wp + 32768 };
    const unsigned short* pBr2[2] = { Wp + 65536,  Wp + 65536  + 16384 };
    const unsigned short* pS1 [2] = { Wp + 98304,  Wp + 98304  + 32768 };
    const unsigned short* pS2 [2] = { Wp + 163840, Wp + 163840 + 16384 };
    const unsigned short* pH  [2] = { Wp + 196608, Wp + 196608 + 32768 };

    pack_w<<<dim3(1024), dim3(256), 0, stream>>>(brW1, brW2, sW1, sW2, hW, Wp);

    // ---- iteration 0 (level 2 -> 1) ----
    hipMemsetAsync(agg, 0, (size_t)n1 * D * sizeof(float), stream);
    edge_mlp<false><<<dim3((n2 + TE - 1) / TE), dim3(256), 0, stream>>>(
        h2, bx2, src2, dst2, pBr1[0], pBr2[0],
        brb1, brg1, brbe1, brb2, brg2, brbe2, agg, n2);
    node_mlp<true><<<dim3((n1 + TE - 1) / TE), dim3(256), 0, stream>>>(
        ax1, agg, pS1[0], pS2[0], pH[0],
        sb1, sg1, sbe1, sb2, sg2, sbe2, hb, hg, hbe, h1, n1);

    // ---- iteration 1 (level 1 -> 0) ----
    hipMemsetAsync(agg, 0, (size_t)n0 * D * sizeof(float), stream);
    edge_mlp<true><<<dim3((n1 + TE - 1) / TE), dim3(256), 0, stream>>>(
        h1, bx1, src1, dst1, pBr1[1], pBr2[1],
        brb1 + D, brg1 + D, brbe1 + D, brb2 + D, brg2 + D, brbe2 + D, agg, n1);
    node_mlp<false><<<dim3((n0 + TE - 1) / TE), dim3(256), 0, stream>>>(
        ax0, agg, pS1[1], pS2[1], pH[1],
        sb1 + D, sg1 + D, sbe1 + D, sb2 + D, sg2 + D, sbe2 + D,
        hb + D, hg + D, hbe + D, d_out, n0);
}

// Round 2
// 715.712 us; speedup vs baseline: 1.0432x; 1.0432x over previous
//
#include <hip/hip_runtime.h>

// TPF encoder, MFMA fp16 version — CSR (sort-by-dst) aggregation, no float atomics.
//
// Round-1 finding: edge_mlp was pinned at 251us regardless of occupancy (66->88%
// changed nothing) with MfmaUtil 5%, VALU 18%, HBM 17% -> bound by the 41M scattered
// fp32 atomicAdds (163 G atomics/s ~= TCC RMW ceiling). This version removes them:
//
// - Once per launch: histogram dst -> 3-phase exclusive scan -> per-edge position
//   (pos[e] = slot in dst-sorted order). Cheap int kernels (~800K int atomics).
// - edge_mlp writes its LN2 output row to ebh[pos[e]] (fp16, coalesced 256B rows).
// - node_mlp fuses segment-sum: node gr sums the CONTIGUOUS ebh rows
//   [inc[gr-1], inc[gr]) in fp32 registers -> fp16 into the LDS agg slot.
//   agg buffer + memsets + fp32 agg read are gone.
// - Fallback: if ws_size can't hold ebh (~106 MB), use the old atomic path.
//
// Carried over: fp16 MFMA 16x16x32, packed weights Wp[kb][n][kk], LDS stride 264,
// s_y aliased into s_x upper half (LDS 17.9KB -> 8 blocks/CU), in-register LN.

#define D   128
#define TE  32
#define XS  264   // s_x row stride in fp16 elems (s_y lives at +128, same stride)

typedef float  f32x4 __attribute__((ext_vector_type(4)));
typedef _Float16 f16x8 __attribute__((ext_vector_type(8)));

__device__ __forceinline__ unsigned short f2h(float f) {
    union { _Float16 h; unsigned short u; } x;
    x.h = (_Float16)f;
    return x.u;
}

// ---- weight pack: Wp[kb*4096 + n*32 + kk] = fp16(W[kb*32+kk][n]) per matrix,level ----
__global__ __launch_bounds__(256) void pack_w(
    const float* __restrict__ brW1, const float* __restrict__ brW2,
    const float* __restrict__ sW1,  const float* __restrict__ sW2,
    const float* __restrict__ hW,   unsigned short* __restrict__ Wp)
{
    int p = blockIdx.x * 256 + threadIdx.x;   // 0 .. 262143
    const float* src; int off, K;
    if (p < 65536)       { src = brW1; off = 0;      K = 256; }
    else if (p < 98304)  { src = brW2; off = 65536;  K = 128; }
    else if (p < 163840) { src = sW1;  off = 98304;  K = 256; }
    else if (p < 196608) { src = sW2;  off = 163840; K = 128; }
    else                 { src = hW;   off = 196608; K = 256; }
    int q = p - off, lvl, r;
    if (K == 256) { lvl = q >> 15; r = q & 32767; }
    else          { lvl = q >> 14; r = q & 16383; }
    int kb = r >> 12, n = (r >> 5) & 127, kk = r & 31;
    Wp[p] = f2h(src[(size_t)lvl * K * 128 + (size_t)(kb * 32 + kk) * 128 + n]);
}

// ================= CSR build (both levels fused; level A at cnt[0..], level B at cnt[AOFF..]) =================

__global__ __launch_bounds__(256) void csr_hist(
    const int* __restrict__ dA, int EA, const int* __restrict__ dB, int EB,
    int* __restrict__ cnt, int AOFFv)
{
    int i = blockIdx.x * 256 + threadIdx.x;
    if (i < EA)               atomicAdd(cnt + dA[i], 1);
    else if (i - EA < EB)     atomicAdd(cnt + AOFFv + dB[i - EA], 1);
}

// per-block (1024 elems) inclusive scan; block sums to bsum (region A slots 0.., B slots 128..)
__global__ __launch_bounds__(256) void csr_scanA(
    const int* __restrict__ cnt, int* __restrict__ inc, int* __restrict__ bsum,
    int nbA, int AOFFv)
{
    __shared__ int lds[256];
    int b = blockIdx.x, t = threadIdx.x;
    int lb, ebase, bs;
    if (b < nbA) { lb = b;       ebase = 0;     bs = lb; }
    else         { lb = b - nbA; ebase = AOFFv; bs = 128 + lb; }
    int idx = ebase + lb * 1024 + t * 4;
    int s0 = cnt[idx], s1 = cnt[idx + 1], s2 = cnt[idx + 2], s3 = cnt[idx + 3];
    int p1 = s0 + s1, p2 = p1 + s2, p3 = p2 + s3;
    lds[t] = p3; __syncthreads();
#pragma unroll
    for (int o = 1; o < 256; o <<= 1) {
        int v = (t >= o) ? lds[t - o] : 0;
        __syncthreads();
        lds[t] += v;
        __syncthreads();
    }
    int ex = lds[t] - p3;
    inc[idx] = ex + s0; inc[idx + 1] = ex + p1; inc[idx + 2] = ex + p2; inc[idx + 3] = ex + p3;
    if (t == 255) bsum[bs] = lds[255];
}

// scan the two bsum regions (<=128 entries each) independently, in-place inclusive
__global__ __launch_bounds__(256) void csr_scanB(int* __restrict__ bsum, int nbA, int nbB)
{
    __shared__ int lds[256];
    int t = threadIdx.x, seg = t >> 7, i = t & 127;
    int n = seg ? nbB : nbA;
    lds[t] = (i < n) ? bsum[t] : 0;
    __syncthreads();
#pragma unroll
    for (int o = 1; o < 128; o <<= 1) {
        int v = (i >= o) ? lds[t - o] : 0;
        __syncthreads();
        lds[t] += v;
        __syncthreads();
    }
    if (i < n) bsum[t] = lds[t];
}

// add block carries -> final inclusive inc; cursor = exclusive start (for pos assignment)
__global__ __launch_bounds__(256) void csr_scanC(
    const int* __restrict__ cnt, int* __restrict__ inc, const int* __restrict__ bsum,
    int* __restrict__ cursor, int nbA, int AOFFv)
{
    int b = blockIdx.x, t = threadIdx.x;
    int lb, ebase, bs;
    if (b < nbA) { lb = b;       ebase = 0;     bs = lb; }
    else         { lb = b - nbA; ebase = AOFFv; bs = 128 + lb; }
    int carry = (lb > 0) ? bsum[bs - 1] : 0;
    int idx = ebase + lb * 1024 + t * 4;
#pragma unroll
    for (int j = 0; j < 4; ++j) {
        int v = inc[idx + j] + carry;
        inc[idx + j] = v;
        cursor[idx + j] = v - cnt[idx + j];
    }
}

__global__ __launch_bounds__(256) void csr_pos(
    const int* __restrict__ dA, int EA, const int* __restrict__ dB, int EB,
    int* __restrict__ cursor, int* __restrict__ posA, int* __restrict__ posB, int AOFFv)
{
    int i = blockIdx.x * 256 + threadIdx.x;
    if (i < EA)           posA[i] = atomicAdd(cursor + dA[i], 1);
    else if (i - EA < EB) posB[i - EA] = atomicAdd(cursor + AOFFv + dB[i - EA], 1);
}

// ================= MLP kernels =================

template<int KB>
__device__ __forceinline__ void gemm_f16(const unsigned short* s_in, int stride,
    const unsigned short* __restrict__ Wp, int rb, int cb, int n15, int q, f32x4 acc[4])
{
    f32x4 zero = {0.f, 0.f, 0.f, 0.f};
#pragma unroll
    for (int ct = 0; ct < 4; ++ct) acc[ct] = zero;
#pragma unroll
    for (int kb = 0; kb < KB; ++kb) {
        f16x8 af = *(const f16x8*)(s_in + (rb + n15) * stride + kb * 32 + q * 8);
        const unsigned short* wb = Wp + (size_t)kb * 4096 + q * 8;
#pragma unroll
        for (int ct = 0; ct < 4; ++ct) {
            f16x8 bf = *(const f16x8*)(wb + (cb + ct * 16 + n15) * 32);
            acc[ct] = __builtin_amdgcn_mfma_f32_16x16x32_f16(af, bf, acc[ct], 0, 0, 0);
        }
    }
}

// bias + LayerNorm + relu, in-place on acc (MFMA C layout: row=rb+q*4+r, col=cb+ct*16+n15)
__device__ __forceinline__ void ln_relu(f32x4 acc[4],
    const float* __restrict__ b, const float* __restrict__ g, const float* __restrict__ be,
    float* s_red, float* s_ms, int rb, int cb, int n15, int q, int wcol, int t)
{
#pragma unroll
    for (int ct = 0; ct < 4; ++ct) {
        float bb = b[cb + ct * 16 + n15];
#pragma unroll
        for (int r = 0; r < 4; ++r) acc[ct][r] += bb;
    }
    float sum[4], ss[4];
#pragma unroll
    for (int r = 0; r < 4; ++r) {
        sum[r] = acc[0][r] + acc[1][r] + acc[2][r] + acc[3][r];
        ss[r]  = acc[0][r]*acc[0][r] + acc[1][r]*acc[1][r]
               + acc[2][r]*acc[2][r] + acc[3][r]*acc[3][r];
    }
#pragma unroll
    for (int off = 1; off < 16; off <<= 1) {
#pragma unroll
        for (int r = 0; r < 4; ++r) {
            sum[r] += __shfl_xor(sum[r], off, 64);
            ss[r]  += __shfl_xor(ss[r],  off, 64);
        }
    }
    if (n15 == 0) {
#pragma unroll
        for (int r = 0; r < 4; ++r) {
            int row = rb + q * 4 + r;
            s_red[row * 4 + wcol * 2 + 0] = sum[r];
            s_red[row * 4 + wcol * 2 + 1] = ss[r];
        }
    }
    __syncthreads();
    if (t < TE) {
        float sm = s_red[t * 4 + 0] + s_red[t * 4 + 2];
        float sq = s_red[t * 4 + 1] + s_red[t * 4 + 3];
        float mean = sm * (1.f / 128.f);
        float var  = sq * (1.f / 128.f) - mean * mean;
        s_ms[t * 2 + 0] = mean;
        s_ms[t * 2 + 1] = rsqrtf(var + 1e-5f);
    }
    __syncthreads();
#pragma unroll
    for (int ct = 0; ct < 4; ++ct) {
        float gg = g[cb + ct * 16 + n15], bb = be[cb + ct * 16 + n15];
#pragma unroll
        for (int r = 0; r < 4; ++r) {
            int row = rb + q * 4 + r;
            float v = (acc[ct][r] - s_ms[row * 2 + 0]) * s_ms[row * 2 + 1] * gg + bb;
            acc[ct][r] = fmaxf(v, 0.f);
        }
    }
}

// CSR: dstpos = pos[] (sorted slot per edge), output to ebh. Fallback: dstpos = dst[], atomics to agg.
template<bool HBF16, bool CSR>
__global__ __launch_bounds__(256, 8) void edge_mlp(
    const void* __restrict__ hsrc, const float* __restrict__ bond,
    const int* __restrict__ src, const int* __restrict__ dstpos,
    const unsigned short* __restrict__ Wp1, const unsigned short* __restrict__ Wp2,
    const float* __restrict__ b1, const float* __restrict__ g1, const float* __restrict__ be1,
    const float* __restrict__ b2, const float* __restrict__ g2, const float* __restrict__ be2,
    float* __restrict__ agg, unsigned short* __restrict__ ebh, int E)
{
    __shared__ unsigned short s_x[TE * XS];
    __shared__ float s_red[TE * 4];
    __shared__ float s_ms[TE * 2];
    __shared__ int s_src[TE], s_idx[TE];
    unsigned short* s_y = s_x + 128;   // aliased f1 buffer (cols 128..255 dead after GEMM1)

    int t = threadIdx.x, eb = blockIdx.x * TE;
    if (t < TE) {
        int ge = eb + t;
        s_src[t] = (ge < E) ? src[ge] : -1;
        s_idx[t] = (ge < E) ? dstpos[ge] : -1;
    }
    __syncthreads();

    if (HBF16) {   // h is fp16 (our h1 intermediate)
        const unsigned short* hp = (const unsigned short*)hsrc;
        for (int c = t; c < TE * 16; c += 256) {
            int row = c >> 4, k8 = c & 15;
            int s = s_src[row];
            uint4 v = make_uint4(0, 0, 0, 0);
            if (s >= 0) v = *(const uint4*)(hp + (size_t)s * 128 + k8 * 8);
            *(uint4*)(s_x + row * XS + k8 * 8) = v;
        }
    } else {       // h is fp32 (input subtree_h_top)
        const float* hp = (const float*)hsrc;
        for (int c = t; c < TE * 32; c += 256) {
            int row = c >> 5, k4 = c & 31;
            int s = s_src[row];
            float4 v = make_float4(0, 0, 0, 0);
            if (s >= 0) v = *(const float4*)(hp + (size_t)s * 128 + k4 * 4);
            ushort4 o; o.x = f2h(v.x); o.y = f2h(v.y); o.z = f2h(v.z); o.w = f2h(v.w);
            *(ushort4*)(s_x + row * XS + k4 * 4) = o;
        }
    }
    for (int c = t; c < TE * 32; c += 256) {   // bond part (always fp32)
        int row = c >> 5, k4 = c & 31;
        int ge = eb + row;
        float4 v = make_float4(0, 0, 0, 0);
        if (ge < E) v = *(const float4*)(bond + (size_t)ge * 128 + k4 * 4);
        ushort4 o; o.x = f2h(v.x); o.y = f2h(v.y); o.z = f2h(v.z); o.w = f2h(v.w);
        *(ushort4*)(s_x + row * XS + 128 + k4 * 4) = o;
    }
    __syncthreads();

    int l = t & 63, w = t >> 6;
    int n15 = l & 15, q = l >> 4;
    int rb = (w & 1) * 16, cb = (w >> 1) * 64, wcol = w >> 1;

    f32x4 acc[4];
    gemm_f16<8>(s_x, XS, Wp1, rb, cb, n15, q, acc);
    ln_relu(acc, b1, g1, be1, s_red, s_ms, rb, cb, n15, q, wcol, t);
    // ln_relu's internal barriers guarantee all waves finished reading s_x before this write
#pragma unroll
    for (int ct = 0; ct < 4; ++ct)
#pragma unroll
        for (int r = 0; r < 4; ++r)
            s_y[(rb + q * 4 + r) * XS + cb + ct * 16 + n15] = f2h(acc[ct][r]);
    __syncthreads();
    gemm_f16<4>(s_y, XS, Wp2, rb, cb, n15, q, acc);
    ln_relu(acc, b2, g2, be2, s_red, s_ms, rb, cb, n15, q, wcol, t);

    if (CSR) {
        // stage fp16 rows in s_x cols 0..127 (all LDS reads are past ln_relu's barriers)
#pragma unroll
        for (int ct = 0; ct < 4; ++ct)
#pragma unroll
            for (int r = 0; r < 4; ++r)
                s_x[(rb + q * 4 + r) * XS + cb + ct * 16 + n15] = f2h(acc[ct][r]);
        __syncthreads();
        for (int c = t; c < TE * 16; c += 256) {   // coalesced 256B row stores to sorted slot
            int row = c >> 4, k8 = c & 15;
            int p = s_idx[row];
            if (p >= 0)
                *(uint4*)(ebh + (size_t)p * 128 + k8 * 8) =
                    *(const uint4*)(s_x + row * XS + k8 * 8);
        }
    } else {
#pragma unroll
        for (int ct = 0; ct < 4; ++ct)
#pragma unroll
            for (int r = 0; r < 4; ++r) {
                int row = rb + q * 4 + r;
                int gd = s_idx[row];
                if (gd >= 0)
                    atomicAdd(agg + (size_t)gd * D + cb + ct * 16 + n15, acc[ct][r]);
            }
    }
}

// CSR: inc = per-node inclusive edge-count scan (this level's base); ebh = sorted edge rows.
template<bool OUT_F16, bool CSR>
__global__ __launch_bounds__(256, 8) void node_mlp(
    const float* __restrict__ ax, const float* __restrict__ agg,
    const int* __restrict__ inc, const unsigned short* __restrict__ ebh,
    const unsigned short* __restrict__ Wp1, const unsigned short* __restrict__ Wp2,
    const unsigned short* __restrict__ Wp3,
    const float* __restrict__ b1, const float* __restrict__ g1, const float* __restrict__ be1,
    const float* __restrict__ b2, const float* __restrict__ g2, const float* __restrict__ be2,
    const float* __restrict__ b3, const float* __restrict__ g3, const float* __restrict__ be3,
    void* __restrict__ out, int N)
{
    __shared__ unsigned short s_x[TE * XS];
    __shared__ float s_red[TE * 4];
    __shared__ float s_ms[TE * 2];
    __shared__ int s_beg[TE], s_end[TE];
    unsigned short* s_y = s_x + 128;   // aliased f1 buffer

    int t = threadIdx.x, nb = blockIdx.x * TE;

    if (CSR && t < TE) {
        int gr = nb + t, b0 = 0, e0 = 0;
        if (gr < N) { e0 = inc[gr]; b0 = (gr == 0) ? 0 : inc[gr - 1]; }
        s_beg[t] = b0; s_end[t] = e0;
    }

    for (int c = t; c < TE * 32; c += 256) {   // ax part
        int row = c >> 5, k4 = c & 31;
        int gr = nb + row;
        float4 v = make_float4(0, 0, 0, 0);
        if (gr < N) v = *(const float4*)(ax + (size_t)gr * 128 + k4 * 4);
        ushort4 o; o.x = f2h(v.x); o.y = f2h(v.y); o.z = f2h(v.z); o.w = f2h(v.w);
        *(ushort4*)(s_x + row * XS + k4 * 4) = o;
    }

    if (CSR) {
        __syncthreads();   // s_beg/s_end visible
        // fused segment-sum: 8 threads per node row, 16 cols each; contiguous ebh rows
        int r = t >> 3, s8 = t & 7;
        float a[16];
#pragma unroll
        for (int k = 0; k < 16; ++k) a[k] = 0.f;
        int jb = s_beg[r], je = s_end[r];
        for (int j = jb; j < je; ++j) {
            const unsigned short* rp = ebh + (size_t)j * 128 + s8 * 16;
            f16x8 v0 = *(const f16x8*)rp;
            f16x8 v1 = *(const f16x8*)(rp + 8);
#pragma unroll
            for (int k = 0; k < 8; ++k) { a[k] += (float)v0[k]; a[8 + k] += (float)v1[k]; }
        }
        f16x8 h0, h1;
#pragma unroll
        for (int k = 0; k < 8; ++k) { h0[k] = (_Float16)a[k]; h1[k] = (_Float16)a[8 + k]; }
        unsigned short* op = s_x + r * XS + 128 + s8 * 16;
        *(f16x8*)op = h0;
        *(f16x8*)(op + 8) = h1;
    } else {
        for (int c = t; c < TE * 32; c += 256) {   // agg part (fp32 buffer)
            int row = c >> 5, k4 = c & 31;
            int gr = nb + row;
            float4 v = make_float4(0, 0, 0, 0);
            if (gr < N) v = *(const float4*)(agg + (size_t)gr * 128 + k4 * 4);
            ushort4 o; o.x = f2h(v.x); o.y = f2h(v.y); o.z = f2h(v.z); o.w = f2h(v.w);
            *(ushort4*)(s_x + row * XS + 128 + k4 * 4) = o;
        }
    }
    __syncthreads();

    int l = t & 63, w = t >> 6;
    int n15 = l & 15, q = l >> 4;
    int rb = (w & 1) * 16, cb = (w >> 1) * 64, wcol = w >> 1;

    f32x4 acc[4];
    gemm_f16<8>(s_x, XS, Wp1, rb, cb, n15, q, acc);
    ln_relu(acc, b1, g1, be1, s_red, s_ms, rb, cb, n15, q, wcol, t);
    // agg half of s_x consumed (barriers in ln_relu) -> safe to overwrite with f1
#pragma unroll
    for (int ct = 0; ct < 4; ++ct)
#pragma unroll
        for (int r = 0; r < 4; ++r)
            s_y[(rb + q * 4 + r) * XS + cb + ct * 16 + n15] = f2h(acc[ct][r]);
    __syncthreads();
    gemm_f16<4>(s_y, XS, Wp2, rb, cb, n15, q, acc);
    ln_relu(acc, b2, g2, be2, s_red, s_ms, rb, cb, n15, q, wcol, t);
#pragma unroll
    for (int ct = 0; ct < 4; ++ct)    // f2 -> s_x cols 128..255 (th = [ax | f2]); f1 dead
#pragma unroll
        for (int r = 0; r < 4; ++r)
            s_x[(rb + q * 4 + r) * XS + 128 + cb + ct * 16 + n15] = f2h(acc[ct][r]);
    __syncthreads();
    gemm_f16<8>(s_x, XS, Wp3, rb, cb, n15, q, acc);
    ln_relu(acc, b3, g3, be3, s_red, s_ms, rb, cb, n15, q, wcol, t);

#pragma unroll
    for (int ct = 0; ct < 4; ++ct)
#pragma unroll
        for (int r = 0; r < 4; ++r) {
            int row = rb + q * 4 + r;
            int gr = nb + row;
            int col = cb + ct * 16 + n15;
            if (gr < N) {
                if (OUT_F16)
                    ((unsigned short*)out)[(size_t)gr * D + col] = f2h(acc[ct][r]);
                else
                    ((float*)out)[(size_t)gr * D + col] = acc[ct][r];
            }
        }
}

extern "C" void kernel_launch(void* const* d_in, const int* in_sizes, int n_in,
                              void* d_out, int out_size, void* d_ws, size_t ws_size,
                              hipStream_t stream)
{
    const float* h2   = (const float*)d_in[0];
    const float* ax1  = (const float*)d_in[1];
    const float* ax0  = (const float*)d_in[2];
    const float* bx2  = (const float*)d_in[3];
    const float* bx1  = (const float*)d_in[4];
    const float* brW1 = (const float*)d_in[5];
    const float* brb1 = (const float*)d_in[6];
    const float* brg1 = (const float*)d_in[7];
    const float* brbe1= (const float*)d_in[8];
    const float* brW2 = (const float*)d_in[9];
    const float* brb2 = (const float*)d_in[10];
    const float* brg2 = (const float*)d_in[11];
    const float* brbe2= (const float*)d_in[12];
    const float* sW1  = (const float*)d_in[13];
    const float* sb1  = (const float*)d_in[14];
    const float* sg1  = (const float*)d_in[15];
    const float* sbe1 = (const float*)d_in[16];
    const float* sW2  = (const float*)d_in[17];
    const float* sb2  = (const float*)d_in[18];
    const float* sg2  = (const float*)d_in[19];
    const float* sbe2 = (const float*)d_in[20];
    const float* hW   = (const float*)d_in[21];
    const float* hb   = (const float*)d_in[22];
    const float* hg   = (const float*)d_in[23];
    const float* hbe  = (const float*)d_in[24];
    const int*   src2 = (const int*)d_in[25];
    const int*   dst2 = (const int*)d_in[26];
    const int*   src1 = (const int*)d_in[27];
    const int*   dst1 = (const int*)d_in[28];

    int n2 = in_sizes[0] / D;
    int n1 = in_sizes[1] / D;
    int n0 = in_sizes[2] / D;

    unsigned short* Wp = (unsigned short*)d_ws;   // 262144 fp16 = 512 KB

    // packed-weight pointers (level stride)
    const unsigned short* pBr1[2] = { Wp + 0,      Wp + 32768 };
    const unsigned short* pBr2[2] = { Wp + 65536,  Wp + 65536  + 16384 };
    const unsigned short* pS1 [2] = { Wp + 98304,  Wp + 98304  + 32768 };
    const unsigned short* pS2 [2] = { Wp + 163840, Wp + 163840 + 16384 };
    const unsigned short* pH  [2] = { Wp + 196608, Wp + 196608 + 32768 };

    // ---- CSR workspace layout ----
    int nbA = (n1 + 1023) / 1024, nbB = (n0 + 1023) / 1024;
    int AOFFv = nbA * 1024;
    size_t AN = (size_t)AOFFv + (size_t)nbB * 1024;
    auto al = [](size_t x) { return (x + 255) & ~(size_t)255; };
    size_t o = 524288;
    size_t cnt_o  = o; o = al(o + AN * 4);
    size_t inc_o  = o; o = al(o + AN * 4);
    size_t cur_o  = o; o = al(o + AN * 4);
    size_t bsum_o = o; o = al(o + 1024);
    size_t posA_o = o; o = al(o + (size_t)n2 * 4);
    size_t posB_o = o; o = al(o + (size_t)n1 * 4);
    size_t h1_o   = o; o = al(o + (size_t)n1 * 256);
    size_t ebh_o  = o; o = al(o + (size_t)n2 * 256);
    bool use_csr = (ws_size >= o) && (nbA <= 128) && (nbB <= 128);

    pack_w<<<dim3(1024), dim3(256), 0, stream>>>(brW1, brW2, sW1, sW2, hW, Wp);

    if (use_csr) {
        int*            cnt    = (int*)((char*)d_ws + cnt_o);
        int*            inc    = (int*)((char*)d_ws + inc_o);
        int*            cursor = (int*)((char*)d_ws + cur_o);
        int*            bsum   = (int*)((char*)d_ws + bsum_o);
        int*            posA   = (int*)((char*)d_ws + posA_o);
        int*            posB   = (int*)((char*)d_ws + posB_o);
        unsigned short* h1     = (unsigned short*)((char*)d_ws + h1_o);
        unsigned short* ebh    = (unsigned short*)((char*)d_ws + ebh_o);

        int EG = (n2 + n1 + 255) / 256;
        hipMemsetAsync(cnt, 0, AN * 4, stream);
        csr_hist <<<dim3(EG),        dim3(256), 0, stream>>>(dst2, n2, dst1, n1, cnt, AOFFv);
        csr_scanA<<<dim3(nbA + nbB), dim3(256), 0, stream>>>(cnt, inc, bsum, nbA, AOFFv);
        csr_scanB<<<dim3(1),         dim3(256), 0, stream>>>(bsum, nbA, nbB);
        csr_scanC<<<dim3(nbA + nbB), dim3(256), 0, stream>>>(cnt, inc, bsum, cursor, nbA, AOFFv);
        csr_pos  <<<dim3(EG),        dim3(256), 0, stream>>>(dst2, n2, dst1, n1, cursor, posA, posB, AOFFv);

        // ---- iteration 0 (level 2 -> 1) ----
        edge_mlp<false, true><<<dim3((n2 + TE - 1) / TE), dim3(256), 0, stream>>>(
            h2, bx2, src2, posA, pBr1[0], pBr2[0],
            brb1, brg1, brbe1, brb2, brg2, brbe2, nullptr, ebh, n2);
        node_mlp<true, true><<<dim3((n1 + TE - 1) / TE), dim3(256), 0, stream>>>(
            ax1, nullptr, inc, ebh, pS1[0], pS2[0], pH[0],
            sb1, sg1, sbe1, sb2, sg2, sbe2, hb, hg, hbe, h1, n1);

        // ---- iteration 1 (level 1 -> 0) ----
        edge_mlp<true, true><<<dim3((n1 + TE - 1) / TE), dim3(256), 0, stream>>>(
            h1, bx1, src1, posB, pBr1[1], pBr2[1],
            brb1 + D, brg1 + D, brbe1 + D, brb2 + D, brg2 + D, brbe2 + D, nullptr, ebh, n1);
        node_mlp<false, true><<<dim3((n0 + TE - 1) / TE), dim3(256), 0, stream>>>(
            ax0, nullptr, inc + AOFFv, ebh, pS1[1], pS2[1], pH[1],
            sb1 + D, sg1 + D, sbe1 + D, sb2 + D, sg2 + D, sbe2 + D,
            hb + D, hg + D, hbe + D, d_out, n0);
    } else {
        // fallback: previous atomic-aggregation path
        float*          agg = (float*)((char*)d_ws + 524288);
        unsigned short* h1  = (unsigned short*)(agg + (size_t)n1 * D);

        hipMemsetAsync(agg, 0, (size_t)n1 * D * sizeof(float), stream);
        edge_mlp<false, false><<<dim3((n2 + TE - 1) / TE), dim3(256), 0, stream>>>(
            h2, bx2, src2, dst2, pBr1[0], pBr2[0],
            brb1, brg1, brbe1, brb2, brg2, brbe2, agg, nullptr, n2);
        node_mlp<true, false><<<dim3((n1 + TE - 1) / TE), dim3(256), 0, stream>>>(
            ax1, agg, nullptr, nullptr, pS1[0], pS2[0], pH[0],
            sb1, sg1, sbe1, sb2, sg2, sbe2, hb, hg, hbe, h1, n1);

        hipMemsetAsync(agg, 0, (size_t)n0 * D * sizeof(float), stream);
        edge_mlp<true, false><<<dim3((n1 + TE - 1) / TE), dim3(256), 0, stream>>>(
            h1, bx1, src1, dst1, pBr1[1], pBr2[1],
            brb1 + D, brg1 + D, brbe1 + D, brb2 + D, brg2 + D, brbe2 + D, agg, nullptr, n1);
        node_mlp<false, false><<<dim3((n0 + TE - 1) / TE), dim3(256), 0, stream>>>(
            ax0, agg, nullptr, nullptr, pS1[1], pS2[1], pH[1],
            sb1 + D, sg1 + D, sbe1 + D, sb2 + D, sg2 + D, sbe2 + D,
            hb + D, hg + D, hbe + D, d_out, n0);
    }
}

// Round 3
// 682.645 us; speedup vs baseline: 1.0937x; 1.0484x over previous
//
#include <hip/hip_runtime.h>

// TPF encoder, MFMA fp16, CSR aggregation (no float atomics), TE=64 big tiles.
//
// Round-2 findings: no pipe saturated (HBM 16%, MFMA 6.4%, VALU 22%); occupancy
// 66->88% did nothing (r1), VGPR cap 64->32 made node kernels ~45us slower (r1).
// => latency-bound on dependent L2 weight loads; per-32-row block reloaded 192KB
// of weights with a 1:1 B-load:MFMA ratio and no VGPR room to pipeline.
// This version: TE=64 rows/block, wave tile 32x64 (acc[2][4]), B-frag reused for
// both row-subtiles (B:MFMA 1:2, weight traffic/row halved), launch_bounds(256,4)
// -> 128 VGPR so the compiler can pipeline B-frags across K-steps and batch the
// staging loads. LDS ~35.8KB -> 4 blocks/CU (occupancy deliberately traded away).
//
// Carried: packed weights Wp[kb][n][kk], LDS stride 264, s_y aliased into s_x
// upper half, in-register LN, CSR sort-by-dst aggregation fused into node_mlp.

#define D   128
#define TE  64
#define XS  264   // s_x row stride in fp16 elems (s_y lives at +128, same stride)

typedef float  f32x4 __attribute__((ext_vector_type(4)));
typedef _Float16 f16x8 __attribute__((ext_vector_type(8)));

__device__ __forceinline__ unsigned short f2h(float f) {
    union { _Float16 h; unsigned short u; } x;
    x.h = (_Float16)f;
    return x.u;
}

// ---- weight pack: Wp[kb*4096 + n*32 + kk] = fp16(W[kb*32+kk][n]) per matrix,level ----
__global__ __launch_bounds__(256) void pack_w(
    const float* __restrict__ brW1, const float* __restrict__ brW2,
    const float* __restrict__ sW1,  const float* __restrict__ sW2,
    const float* __restrict__ hW,   unsigned short* __restrict__ Wp)
{
    int p = blockIdx.x * 256 + threadIdx.x;   // 0 .. 262143
    const float* src; int off, K;
    if (p < 65536)       { src = brW1; off = 0;      K = 256; }
    else if (p < 98304)  { src = brW2; off = 65536;  K = 128; }
    else if (p < 163840) { src = sW1;  off = 98304;  K = 256; }
    else if (p < 196608) { src = sW2;  off = 163840; K = 128; }
    else                 { src = hW;   off = 196608; K = 256; }
    int q = p - off, lvl, r;
    if (K == 256) { lvl = q >> 15; r = q & 32767; }
    else          { lvl = q >> 14; r = q & 16383; }
    int kb = r >> 12, n = (r >> 5) & 127, kk = r & 31;
    Wp[p] = f2h(src[(size_t)lvl * K * 128 + (size_t)(kb * 32 + kk) * 128 + n]);
}

// ================= CSR build (levels fused; A at cnt[0..], B at cnt[AOFF..]) =================

__global__ __launch_bounds__(256) void csr_hist(
    const int* __restrict__ dA, int EA, const int* __restrict__ dB, int EB,
    int* __restrict__ cnt, int AOFFv)
{
    int i = blockIdx.x * 256 + threadIdx.x;
    if (i < EA)               atomicAdd(cnt + dA[i], 1);
    else if (i - EA < EB)     atomicAdd(cnt + AOFFv + dB[i - EA], 1);
}

__global__ __launch_bounds__(256) void csr_scanA(
    const int* __restrict__ cnt, int* __restrict__ inc, int* __restrict__ bsum,
    int nbA, int AOFFv)
{
    __shared__ int lds[256];
    int b = blockIdx.x, t = threadIdx.x;
    int lb, ebase, bs;
    if (b < nbA) { lb = b;       ebase = 0;     bs = lb; }
    else         { lb = b - nbA; ebase = AOFFv; bs = 128 + lb; }
    int idx = ebase + lb * 1024 + t * 4;
    int s0 = cnt[idx], s1 = cnt[idx + 1], s2 = cnt[idx + 2], s3 = cnt[idx + 3];
    int p1 = s0 + s1, p2 = p1 + s2, p3 = p2 + s3;
    lds[t] = p3; __syncthreads();
#pragma unroll
    for (int o = 1; o < 256; o <<= 1) {
        int v = (t >= o) ? lds[t - o] : 0;
        __syncthreads();
        lds[t] += v;
        __syncthreads();
    }
    int ex = lds[t] - p3;
    inc[idx] = ex + s0; inc[idx + 1] = ex + p1; inc[idx + 2] = ex + p2; inc[idx + 3] = ex + p3;
    if (t == 255) bsum[bs] = lds[255];
}

__global__ __launch_bounds__(256) void csr_scanB(int* __restrict__ bsum, int nbA, int nbB)
{
    __shared__ int lds[256];
    int t = threadIdx.x, seg = t >> 7, i = t & 127;
    int n = seg ? nbB : nbA;
    lds[t] = (i < n) ? bsum[t] : 0;
    __syncthreads();
#pragma unroll
    for (int o = 1; o < 128; o <<= 1) {
        int v = (i >= o) ? lds[t - o] : 0;
        __syncthreads();
        lds[t] += v;
        __syncthreads();
    }
    if (i < n) bsum[t] = lds[t];
}

__global__ __launch_bounds__(256) void csr_scanC(
    const int* __restrict__ cnt, int* __restrict__ inc, const int* __restrict__ bsum,
    int* __restrict__ cursor, int nbA, int AOFFv)
{
    int b = blockIdx.x, t = threadIdx.x;
    int lb, ebase, bs;
    if (b < nbA) { lb = b;       ebase = 0;     bs = lb; }
    else         { lb = b - nbA; ebase = AOFFv; bs = 128 + lb; }
    int carry = (lb > 0) ? bsum[bs - 1] : 0;
    int idx = ebase + lb * 1024 + t * 4;
#pragma unroll
    for (int j = 0; j < 4; ++j) {
        int v = inc[idx + j] + carry;
        inc[idx + j] = v;
        cursor[idx + j] = v - cnt[idx + j];
    }
}

__global__ __launch_bounds__(256) void csr_pos(
    const int* __restrict__ dA, int EA, const int* __restrict__ dB, int EB,
    int* __restrict__ cursor, int* __restrict__ posA, int* __restrict__ posB, int AOFFv)
{
    int i = blockIdx.x * 256 + threadIdx.x;
    if (i < EA)           posA[i] = atomicAdd(cursor + dA[i], 1);
    else if (i - EA < EB) posB[i - EA] = atomicAdd(cursor + AOFFv + dB[i - EA], 1);
}

// ================= MLP kernels =================

// wave tile: 32 rows (rb + m*16 + q*4 + r) x 64 cols (cb + ct*16 + n15)
template<int KB>
__device__ __forceinline__ void gemm_f16(const unsigned short* s_in, int stride,
    const unsigned short* __restrict__ Wp, int rb, int cb, int n15, int q, f32x4 acc[2][4])
{
    f32x4 zero = {0.f, 0.f, 0.f, 0.f};
#pragma unroll
    for (int m = 0; m < 2; ++m)
#pragma unroll
        for (int ct = 0; ct < 4; ++ct) acc[m][ct] = zero;
#pragma unroll
    for (int kb = 0; kb < KB; ++kb) {
        f16x8 af0 = *(const f16x8*)(s_in + (rb + n15) * stride + kb * 32 + q * 8);
        f16x8 af1 = *(const f16x8*)(s_in + (rb + 16 + n15) * stride + kb * 32 + q * 8);
        const unsigned short* wb = Wp + (size_t)kb * 4096 + q * 8;
#pragma unroll
        for (int ct = 0; ct < 4; ++ct) {
            f16x8 bf = *(const f16x8*)(wb + (cb + ct * 16 + n15) * 32);
            acc[0][ct] = __builtin_amdgcn_mfma_f32_16x16x32_f16(af0, bf, acc[0][ct], 0, 0, 0);
            acc[1][ct] = __builtin_amdgcn_mfma_f32_16x16x32_f16(af1, bf, acc[1][ct], 0, 0, 0);
        }
    }
}

// bias + LayerNorm + relu, in-place on acc
__device__ __forceinline__ void ln_relu(f32x4 acc[2][4],
    const float* __restrict__ b, const float* __restrict__ g, const float* __restrict__ be,
    float* s_red, float* s_ms, int rb, int cb, int n15, int q, int wcol, int t)
{
#pragma unroll
    for (int ct = 0; ct < 4; ++ct) {
        float bb = b[cb + ct * 16 + n15];
#pragma unroll
        for (int m = 0; m < 2; ++m)
#pragma unroll
            for (int r = 0; r < 4; ++r) acc[m][ct][r] += bb;
    }
    float sum[2][4], ss[2][4];
#pragma unroll
    for (int m = 0; m < 2; ++m)
#pragma unroll
        for (int r = 0; r < 4; ++r) {
            sum[m][r] = acc[m][0][r] + acc[m][1][r] + acc[m][2][r] + acc[m][3][r];
            ss[m][r]  = acc[m][0][r]*acc[m][0][r] + acc[m][1][r]*acc[m][1][r]
                      + acc[m][2][r]*acc[m][2][r] + acc[m][3][r]*acc[m][3][r];
        }
#pragma unroll
    for (int off = 1; off < 16; off <<= 1) {
#pragma unroll
        for (int m = 0; m < 2; ++m)
#pragma unroll
            for (int r = 0; r < 4; ++r) {
                sum[m][r] += __shfl_xor(sum[m][r], off, 64);
                ss[m][r]  += __shfl_xor(ss[m][r],  off, 64);
            }
    }
    if (n15 == 0) {
#pragma unroll
        for (int m = 0; m < 2; ++m)
#pragma unroll
            for (int r = 0; r < 4; ++r) {
                int row = rb + m * 16 + q * 4 + r;
                s_red[row * 4 + wcol * 2 + 0] = sum[m][r];
                s_red[row * 4 + wcol * 2 + 1] = ss[m][r];
            }
    }
    __syncthreads();
    if (t < TE) {
        float sm = s_red[t * 4 + 0] + s_red[t * 4 + 2];
        float sq = s_red[t * 4 + 1] + s_red[t * 4 + 3];
        float mean = sm * (1.f / 128.f);
        float var  = sq * (1.f / 128.f) - mean * mean;
        s_ms[t * 2 + 0] = mean;
        s_ms[t * 2 + 1] = rsqrtf(var + 1e-5f);
    }
    __syncthreads();
#pragma unroll
    for (int ct = 0; ct < 4; ++ct) {
        float gg = g[cb + ct * 16 + n15], bb = be[cb + ct * 16 + n15];
#pragma unroll
        for (int m = 0; m < 2; ++m)
#pragma unroll
            for (int r = 0; r < 4; ++r) {
                int row = rb + m * 16 + q * 4 + r;
                float v = (acc[m][ct][r] - s_ms[row * 2 + 0]) * s_ms[row * 2 + 1] * gg + bb;
                acc[m][ct][r] = fmaxf(v, 0.f);
            }
    }
}

// CSR: dstpos = pos[] (sorted slot per edge), output to ebh. Fallback: dstpos = dst[], atomics.
template<bool HBF16, bool CSR>
__global__ __launch_bounds__(256, 4) void edge_mlp(
    const void* __restrict__ hsrc, const float* __restrict__ bond,
    const int* __restrict__ src, const int* __restrict__ dstpos,
    const unsigned short* __restrict__ Wp1, const unsigned short* __restrict__ Wp2,
    const float* __restrict__ b1, const float* __restrict__ g1, const float* __restrict__ be1,
    const float* __restrict__ b2, const float* __restrict__ g2, const float* __restrict__ be2,
    float* __restrict__ agg, unsigned short* __restrict__ ebh, int E)
{
    __shared__ unsigned short s_x[TE * XS];
    __shared__ float s_red[TE * 4];
    __shared__ float s_ms[TE * 2];
    __shared__ int s_src[TE], s_idx[TE];
    unsigned short* s_y = s_x + 128;   // aliased f1 buffer (cols 128..255 dead after GEMM1)

    int t = threadIdx.x, eb = blockIdx.x * TE;
    if (t < TE) {
        int ge = eb + t;
        s_src[t] = (ge < E) ? src[ge] : -1;
        s_idx[t] = (ge < E) ? dstpos[ge] : -1;
    }
    __syncthreads();

    if (HBF16) {   // h is fp16 (our h1 intermediate)
        const unsigned short* hp = (const unsigned short*)hsrc;
        for (int c = t; c < TE * 16; c += 256) {
            int row = c >> 4, k8 = c & 15;
            int s = s_src[row];
            uint4 v = make_uint4(0, 0, 0, 0);
            if (s >= 0) v = *(const uint4*)(hp + (size_t)s * 128 + k8 * 8);
            *(uint4*)(s_x + row * XS + k8 * 8) = v;
        }
    } else {       // h is fp32 (input subtree_h_top)
        const float* hp = (const float*)hsrc;
        for (int c = t; c < TE * 32; c += 256) {
            int row = c >> 5, k4 = c & 31;
            int s = s_src[row];
            float4 v = make_float4(0, 0, 0, 0);
            if (s >= 0) v = *(const float4*)(hp + (size_t)s * 128 + k4 * 4);
            ushort4 o; o.x = f2h(v.x); o.y = f2h(v.y); o.z = f2h(v.z); o.w = f2h(v.w);
            *(ushort4*)(s_x + row * XS + k4 * 4) = o;
        }
    }
    for (int c = t; c < TE * 32; c += 256) {   // bond part (always fp32)
        int row = c >> 5, k4 = c & 31;
        int ge = eb + row;
        float4 v = make_float4(0, 0, 0, 0);
        if (ge < E) v = *(const float4*)(bond + (size_t)ge * 128 + k4 * 4);
        ushort4 o; o.x = f2h(v.x); o.y = f2h(v.y); o.z = f2h(v.z); o.w = f2h(v.w);
        *(ushort4*)(s_x + row * XS + 128 + k4 * 4) = o;
    }
    __syncthreads();

    int l = t & 63, w = t >> 6;
    int n15 = l & 15, q = l >> 4;
    int rb = (w & 1) * 32, cb = (w >> 1) * 64, wcol = w >> 1;

    f32x4 acc[2][4];
    gemm_f16<8>(s_x, XS, Wp1, rb, cb, n15, q, acc);
    ln_relu(acc, b1, g1, be1, s_red, s_ms, rb, cb, n15, q, wcol, t);
    // ln_relu's barriers guarantee all waves finished reading s_x before this write
#pragma unroll
    for (int m = 0; m < 2; ++m)
#pragma unroll
        for (int ct = 0; ct < 4; ++ct)
#pragma unroll
            for (int r = 0; r < 4; ++r)
                s_y[(rb + m * 16 + q * 4 + r) * XS + cb + ct * 16 + n15] = f2h(acc[m][ct][r]);
    __syncthreads();
    gemm_f16<4>(s_y, XS, Wp2, rb, cb, n15, q, acc);
    ln_relu(acc, b2, g2, be2, s_red, s_ms, rb, cb, n15, q, wcol, t);

    if (CSR) {
        // stage fp16 rows in s_x cols 0..127 (all LDS reads are past ln_relu's barriers)
#pragma unroll
        for (int m = 0; m < 2; ++m)
#pragma unroll
            for (int ct = 0; ct < 4; ++ct)
#pragma unroll
                for (int r = 0; r < 4; ++r)
                    s_x[(rb + m * 16 + q * 4 + r) * XS + cb + ct * 16 + n15] = f2h(acc[m][ct][r]);
        __syncthreads();
        for (int c = t; c < TE * 16; c += 256) {   // coalesced 256B row stores to sorted slot
            int row = c >> 4, k8 = c & 15;
            int p = s_idx[row];
            if (p >= 0)
                *(uint4*)(ebh + (size_t)p * 128 + k8 * 8) =
                    *(const uint4*)(s_x + row * XS + k8 * 8);
        }
    } else {
#pragma unroll
        for (int m = 0; m < 2; ++m)
#pragma unroll
            for (int ct = 0; ct < 4; ++ct)
#pragma unroll
                for (int r = 0; r < 4; ++r) {
                    int row = rb + m * 16 + q * 4 + r;
                    int gd = s_idx[row];
                    if (gd >= 0)
                        atomicAdd(agg + (size_t)gd * D + cb + ct * 16 + n15, acc[m][ct][r]);
                }
    }
}

// CSR: inc = per-node inclusive edge-count scan; ebh = dst-sorted edge rows.
template<bool OUT_F16, bool CSR>
__global__ __launch_bounds__(256, 4) void node_mlp(
    const float* __restrict__ ax, const float* __restrict__ agg,
    const int* __restrict__ inc, const unsigned short* __restrict__ ebh,
    const unsigned short* __restrict__ Wp1, const unsigned short* __restrict__ Wp2,
    const unsigned short* __restrict__ Wp3,
    const float* __restrict__ b1, const float* __restrict__ g1, const float* __restrict__ be1,
    const float* __restrict__ b2, const float* __restrict__ g2, const float* __restrict__ be2,
    const float* __restrict__ b3, const float* __restrict__ g3, const float* __restrict__ be3,
    void* __restrict__ out, int N)
{
    __shared__ unsigned short s_x[TE * XS];
    __shared__ float s_red[TE * 4];
    __shared__ float s_ms[TE * 2];
    __shared__ int s_beg[TE], s_end[TE];
    unsigned short* s_y = s_x + 128;   // aliased f1 buffer

    int t = threadIdx.x, nb = blockIdx.x * TE;

    if (CSR && t < TE) {
        int gr = nb + t, b0 = 0, e0 = 0;
        if (gr < N) { e0 = inc[gr]; b0 = (gr == 0) ? 0 : inc[gr - 1]; }
        s_beg[t] = b0; s_end[t] = e0;
    }

    for (int c = t; c < TE * 32; c += 256) {   // ax part
        int row = c >> 5, k4 = c & 31;
        int gr = nb + row;
        float4 v = make_float4(0, 0, 0, 0);
        if (gr < N) v = *(const float4*)(ax + (size_t)gr * 128 + k4 * 4);
        ushort4 o; o.x = f2h(v.x); o.y = f2h(v.y); o.z = f2h(v.z); o.w = f2h(v.w);
        *(ushort4*)(s_x + row * XS + k4 * 4) = o;
    }

    if (CSR) {
        __syncthreads();   // s_beg/s_end visible
        // fused segment-sum: 4 threads per node row, 32 cols each; contiguous ebh rows
        int r = t >> 2, s4 = t & 3;
        float a[32];
#pragma unroll
        for (int k = 0; k < 32; ++k) a[k] = 0.f;
        int jb = s_beg[r], je = s_end[r];
        for (int j = jb; j < je; ++j) {
            const unsigned short* rp = ebh + (size_t)j * 128 + s4 * 32;
            f16x8 v0 = *(const f16x8*)rp;
            f16x8 v1 = *(const f16x8*)(rp + 8);
            f16x8 v2 = *(const f16x8*)(rp + 16);
            f16x8 v3 = *(const f16x8*)(rp + 24);
#pragma unroll
            for (int k = 0; k < 8; ++k) {
                a[k]      += (float)v0[k];
                a[8 + k]  += (float)v1[k];
                a[16 + k] += (float)v2[k];
                a[24 + k] += (float)v3[k];
            }
        }
        unsigned short* op = s_x + r * XS + 128 + s4 * 32;
#pragma unroll
        for (int blk = 0; blk < 4; ++blk) {
            f16x8 h;
#pragma unroll
            for (int k = 0; k < 8; ++k) h[k] = (_Float16)a[blk * 8 + k];
            *(f16x8*)(op + blk * 8) = h;
        }
    } else {
        for (int c = t; c < TE * 32; c += 256) {   // agg part (fp32 buffer)
            int row = c >> 5, k4 = c & 31;
            int gr = nb + row;
            float4 v = make_float4(0, 0, 0, 0);
            if (gr < N) v = *(const float4*)(agg + (size_t)gr * 128 + k4 * 4);
            ushort4 o; o.x = f2h(v.x); o.y = f2h(v.y); o.z = f2h(v.z); o.w = f2h(v.w);
            *(ushort4*)(s_x + row * XS + 128 + k4 * 4) = o;
        }
    }
    __syncthreads();

    int l = t & 63, w = t >> 6;
    int n15 = l & 15, q = l >> 4;
    int rb = (w & 1) * 32, cb = (w >> 1) * 64, wcol = w >> 1;

    f32x4 acc[2][4];
    gemm_f16<8>(s_x, XS, Wp1, rb, cb, n15, q, acc);
    ln_relu(acc, b1, g1, be1, s_red, s_ms, rb, cb, n15, q, wcol, t);
    // agg half of s_x consumed (barriers in ln_relu) -> safe to overwrite with f1
#pragma unroll
    for (int m = 0; m < 2; ++m)
#pragma unroll
        for (int ct = 0; ct < 4; ++ct)
#pragma unroll
            for (int r = 0; r < 4; ++r)
                s_y[(rb + m * 16 + q * 4 + r) * XS + cb + ct * 16 + n15] = f2h(acc[m][ct][r]);
    __syncthreads();
    gemm_f16<4>(s_y, XS, Wp2, rb, cb, n15, q, acc);
    ln_relu(acc, b2, g2, be2, s_red, s_ms, rb, cb, n15, q, wcol, t);
#pragma unroll
    for (int m = 0; m < 2; ++m)    // f2 -> s_x cols 128..255 (th = [ax | f2]); f1 dead
#pragma unroll
        for (int ct = 0; ct < 4; ++ct)
#pragma unroll
            for (int r = 0; r < 4; ++r)
                s_x[(rb + m * 16 + q * 4 + r) * XS + 128 + cb + ct * 16 + n15] = f2h(acc[m][ct][r]);
    __syncthreads();
    gemm_f16<8>(s_x, XS, Wp3, rb, cb, n15, q, acc);
    ln_relu(acc, b3, g3, be3, s_red, s_ms, rb, cb, n15, q, wcol, t);

#pragma unroll
    for (int m = 0; m < 2; ++m)
#pragma unroll
        for (int ct = 0; ct < 4; ++ct)
#pragma unroll
            for (int r = 0; r < 4; ++r) {
                int row = rb + m * 16 + q * 4 + r;
                int gr = nb + row;
                int col = cb + ct * 16 + n15;
                if (gr < N) {
                    if (OUT_F16)
                        ((unsigned short*)out)[(size_t)gr * D + col] = f2h(acc[m][ct][r]);
                    else
                        ((float*)out)[(size_t)gr * D + col] = acc[m][ct][r];
                }
            }
}

extern "C" void kernel_launch(void* const* d_in, const int* in_sizes, int n_in,
                              void* d_out, int out_size, void* d_ws, size_t ws_size,
                              hipStream_t stream)
{
    const float* h2   = (const float*)d_in[0];
    const float* ax1  = (const float*)d_in[1];
    const float* ax0  = (const float*)d_in[2];
    const float* bx2  = (const float*)d_in[3];
    const float* bx1  = (const float*)d_in[4];
    const float* brW1 = (const float*)d_in[5];
    const float* brb1 = (const float*)d_in[6];
    const float* brg1 = (const float*)d_in[7];
    const float* brbe1= (const float*)d_in[8];
    const float* brW2 = (const float*)d_in[9];
    const float* brb2 = (const float*)d_in[10];
    const float* brg2 = (const float*)d_in[11];
    const float* brbe2= (const float*)d_in[12];
    const float* sW1  = (const float*)d_in[13];
    const float* sb1  = (const float*)d_in[14];
    const float* sg1  = (const float*)d_in[15];
    const float* sbe1 = (const float*)d_in[16];
    const float* sW2  = (const float*)d_in[17];
    const float* sb2  = (const float*)d_in[18];
    const float* sg2  = (const float*)d_in[19];
    const float* sbe2 = (const float*)d_in[20];
    const float* hW   = (const float*)d_in[21];
    const float* hb   = (const float*)d_in[22];
    const float* hg   = (const float*)d_in[23];
    const float* hbe  = (const float*)d_in[24];
    const int*   src2 = (const int*)d_in[25];
    const int*   dst2 = (const int*)d_in[26];
    const int*   src1 = (const int*)d_in[27];
    const int*   dst1 = (const int*)d_in[28];

    int n2 = in_sizes[0] / D;
    int n1 = in_sizes[1] / D;
    int n0 = in_sizes[2] / D;

    unsigned short* Wp = (unsigned short*)d_ws;   // 262144 fp16 = 512 KB

    // packed-weight pointers (level stride)
    const unsigned short* pBr1[2] = { Wp + 0,      Wp + 32768 };
    const unsigned short* pBr2[2] = { Wp + 65536,  Wp + 65536  + 16384 };
    const unsigned short* pS1 [2] = { Wp + 98304,  Wp + 98304  + 32768 };
    const unsigned short* pS2 [2] = { Wp + 163840, Wp + 163840 + 16384 };
    const unsigned short* pH  [2] = { Wp + 196608, Wp + 196608 + 32768 };

    // ---- CSR workspace layout ----
    int nbA = (n1 + 1023) / 1024, nbB = (n0 + 1023) / 1024;
    int AOFFv = nbA * 1024;
    size_t AN = (size_t)AOFFv + (size_t)nbB * 1024;
    auto al = [](size_t x) { return (x + 255) & ~(size_t)255; };
    size_t o = 524288;
    size_t cnt_o  = o; o = al(o + AN * 4);
    size_t inc_o  = o; o = al(o + AN * 4);
    size_t cur_o  = o; o = al(o + AN * 4);
    size_t bsum_o = o; o = al(o + 1024);
    size_t posA_o = o; o = al(o + (size_t)n2 * 4);
    size_t posB_o = o; o = al(o + (size_t)n1 * 4);
    size_t h1_o   = o; o = al(o + (size_t)n1 * 256);
    size_t ebh_o  = o; o = al(o + (size_t)n2 * 256);
    bool use_csr = (ws_size >= o) && (nbA <= 128) && (nbB <= 128);

    pack_w<<<dim3(1024), dim3(256), 0, stream>>>(brW1, brW2, sW1, sW2, hW, Wp);

    if (use_csr) {
        int*            cnt    = (int*)((char*)d_ws + cnt_o);
        int*            inc    = (int*)((char*)d_ws + inc_o);
        int*            cursor = (int*)((char*)d_ws + cur_o);
        int*            bsum   = (int*)((char*)d_ws + bsum_o);
        int*            posA   = (int*)((char*)d_ws + posA_o);
        int*            posB   = (int*)((char*)d_ws + posB_o);
        unsigned short* h1     = (unsigned short*)((char*)d_ws + h1_o);
        unsigned short* ebh    = (unsigned short*)((char*)d_ws + ebh_o);

        int EG = (n2 + n1 + 255) / 256;
        hipMemsetAsync(cnt, 0, AN * 4, stream);
        csr_hist <<<dim3(EG),        dim3(256), 0, stream>>>(dst2, n2, dst1, n1, cnt, AOFFv);
        csr_scanA<<<dim3(nbA + nbB), dim3(256), 0, stream>>>(cnt, inc, bsum, nbA, AOFFv);
        csr_scanB<<<dim3(1),         dim3(256), 0, stream>>>(bsum, nbA, nbB);
        csr_scanC<<<dim3(nbA + nbB), dim3(256), 0, stream>>>(cnt, inc, bsum, cursor, nbA, AOFFv);
        csr_pos  <<<dim3(EG),        dim3(256), 0, stream>>>(dst2, n2, dst1, n1, cursor, posA, posB, AOFFv);

        // ---- iteration 0 (level 2 -> 1) ----
        edge_mlp<false, true><<<dim3((n2 + TE - 1) / TE), dim3(256), 0, stream>>>(
            h2, bx2, src2, posA, pBr1[0], pBr2[0],
            brb1, brg1, brbe1, brb2, brg2, brbe2, nullptr, ebh, n2);
        node_mlp<true, true><<<dim3((n1 + TE - 1) / TE), dim3(256), 0, stream>>>(
            ax1, nullptr, inc, ebh, pS1[0], pS2[0], pH[0],
            sb1, sg1, sbe1, sb2, sg2, sbe2, hb, hg, hbe, h1, n1);

        // ---- iteration 1 (level 1 -> 0) ----
        edge_mlp<true, true><<<dim3((n1 + TE - 1) / TE), dim3(256), 0, stream>>>(
            h1, bx1, src1, posB, pBr1[1], pBr2[1],
            brb1 + D, brg1 + D, brbe1 + D, brb2 + D, brg2 + D, brbe2 + D, nullptr, ebh, n1);
        node_mlp<false, true><<<dim3((n0 + TE - 1) / TE), dim3(256), 0, stream>>>(
            ax0, nullptr, inc + AOFFv, ebh, pS1[1], pS2[1], pH[1],
            sb1 + D, sg1 + D, sbe1 + D, sb2 + D, sg2 + D, sbe2 + D,
            hb + D, hg + D, hbe + D, d_out, n0);
    } else {
        // fallback: atomic-aggregation path
        float*          agg = (float*)((char*)d_ws + 524288);
        unsigned short* h1  = (unsigned short*)(agg + (size_t)n1 * D);

        hipMemsetAsync(agg, 0, (size_t)n1 * D * sizeof(float), stream);
        edge_mlp<false, false><<<dim3((n2 + TE - 1) / TE), dim3(256), 0, stream>>>(
            h2, bx2, src2, dst2, pBr1[0], pBr2[0],
            brb1, brg1, brbe1, brb2, brg2, brbe2, agg, nullptr, n2);
        node_mlp<true, false><<<dim3((n1 + TE - 1) / TE), dim3(256), 0, stream>>>(
            ax1, agg, nullptr, nullptr, pS1[0], pS2[0], pH[0],
            sb1, sg1, sbe1, sb2, sg2, sbe2, hb, hg, hbe, h1, n1);

        hipMemsetAsync(agg, 0, (size_t)n0 * D * sizeof(float), stream);
        edge_mlp<true, false><<<dim3((n1 + TE - 1) / TE), dim3(256), 0, stream>>>(
            h1, bx1, src1, dst1, pBr1[1], pBr2[1],
            brb1 + D, brg1 + D, brbe1 + D, brb2 + D, brg2 + D, brbe2 + D, agg, nullptr, n1);
        node_mlp<false, false><<<dim3((n0 + TE - 1) / TE), dim3(256), 0, stream>>>(
            ax0, agg, nullptr, nullptr, pS1[1], pS2[1], pH[1],
            sb1 + D, sg1 + D, sbe1 + D, sb2 + D, sg2 + D, sbe2 + D,
            hb + D, hg + D, hbe + D, d_out, n0);
    }
}